// Round 1
// baseline (2671.158 us; speedup 1.0000x reference)
//
#include <hip/hip_runtime.h>
#include <hip/hip_bf16.h>
#include <cstdint>

typedef __attribute__((ext_vector_type(8))) short short8;
typedef __attribute__((ext_vector_type(4))) float f32x4;

#define SLOPE 0.01f
#define FC_K 571520
#define FC_CH 559
#define FC_NB 1024

__device__ __forceinline__ unsigned short f2bf(float f) {
    union { float f; unsigned u; } v; v.f = f;
    unsigned r = v.u + 0x7fffu + ((v.u >> 16) & 1u);
    return (unsigned short)(r >> 16);
}
__device__ __forceinline__ float bf2f(unsigned short h) {
    union { unsigned u; float f; } v; v.u = ((unsigned)h) << 16;
    return v.f;
}
__device__ __forceinline__ float leaky(float x) { return x >= 0.f ? x : SLOPE * x; }

// ---- repack conv2 weights [3,3,32,64] fp32 -> bf16 MFMA B-fragments ----
// Bfrag[tap][nt][lane][j] = w2[tap][ci=(lane>>4)*8+j][co=nt*16+(lane&15)]
__global__ void k_prep_wf(const float* __restrict__ w2, unsigned short* __restrict__ wf) {
    int tid = blockIdx.x * 256 + threadIdx.x;
    if (tid >= 9 * 4 * 64) return;
    int tap = tid >> 8;
    int r = tid & 255;
    int nt = r >> 6;
    int lane = r & 63;
    int ci0 = (lane >> 4) * 8;
    int co = nt * 16 + (lane & 15);
#pragma unroll
    for (int j = 0; j < 8; ++j) {
        float v = w2[(tap * 32 + ci0 + j) * 64 + co];
        wf[((tap * 4 + nt) * 64 + lane) * 8 + j] = f2bf(v);
    }
}

// ---- conv1 (3x3x1->32, valid) + relu + maxpool2 fused. out bf16 [16,97,383,32] ----
__global__ void k_conv1pool(const float* __restrict__ hid, const float* __restrict__ w1,
                            const float* __restrict__ b1, unsigned short* __restrict__ x1) {
    int tid = blockIdx.x * 256 + threadIdx.x;
    int c = tid & 31;
    int t2 = tid >> 5;
    int ow = t2 % 383;
    int t3 = t2 / 383;
    int oh = t3 % 97;
    int b = t3 / 97;
    float wt[9];
#pragma unroll
    for (int k = 0; k < 9; ++k) wt[k] = w1[k * 32 + c];
    const float* hp = hid + ((size_t)(b * 197 + 2 * oh)) * 768 + 2 * ow;
    float in[4][4];
#pragma unroll
    for (int di = 0; di < 4; ++di)
#pragma unroll
        for (int dj = 0; dj < 4; ++dj) in[di][dj] = hp[di * 768 + dj];
    float bias = b1[c];
    float m = 0.f;  // relu floor
#pragma unroll
    for (int dh = 0; dh < 2; ++dh)
#pragma unroll
        for (int dw = 0; dw < 2; ++dw) {
            float s = bias;
#pragma unroll
            for (int kh = 0; kh < 3; ++kh)
#pragma unroll
                for (int kw = 0; kw < 3; ++kw)
                    s += in[dh + kh][dw + kw] * wt[kh * 3 + kw];
            m = fmaxf(m, s);
        }
    x1[tid] = f2bf(m);
}

// ---- conv2 implicit-GEMM MFMA: out pixels (b,oh,ow) x co. out bf16 [16,95,381,64] ----
__global__ void k_conv2(const unsigned short* __restrict__ x1, const unsigned short* __restrict__ wf,
                        const float* __restrict__ b2, unsigned short* __restrict__ out) {
    int g = blockIdx.x;
    int grp = g % 6;
    int t = g / 6;
    int oh = t % 95;
    int b = t / 95;
    int wave = threadIdx.x >> 6;
    int lane = threadIdx.x & 63;
    int ow0 = (grp * 4 + wave) * 16;
    int row = lane & 15;   // A m-index = output pixel within tile
    int quad = lane >> 4;  // A k-group
    f32x4 acc0 = {0,0,0,0}, acc1 = {0,0,0,0}, acc2 = {0,0,0,0}, acc3 = {0,0,0,0};
#pragma unroll
    for (int tap = 0; tap < 9; ++tap) {
        int kh = tap / 3, kw = tap % 3;
        const short8 av = *(const short8*)(x1 +
            (((size_t)(b * 97 + oh + kh) * 383) + ow0 + row + kw) * 32 + quad * 8);
        const short8 bv0 = *(const short8*)(wf + ((tap * 4 + 0) * 64 + lane) * 8);
        const short8 bv1 = *(const short8*)(wf + ((tap * 4 + 1) * 64 + lane) * 8);
        const short8 bv2 = *(const short8*)(wf + ((tap * 4 + 2) * 64 + lane) * 8);
        const short8 bv3 = *(const short8*)(wf + ((tap * 4 + 3) * 64 + lane) * 8);
        acc0 = __builtin_amdgcn_mfma_f32_16x16x32_bf16(av, bv0, acc0, 0, 0, 0);
        acc1 = __builtin_amdgcn_mfma_f32_16x16x32_bf16(av, bv1, acc1, 0, 0, 0);
        acc2 = __builtin_amdgcn_mfma_f32_16x16x32_bf16(av, bv2, acc2, 0, 0, 0);
        acc3 = __builtin_amdgcn_mfma_f32_16x16x32_bf16(av, bv3, acc3, 0, 0, 0);
    }
    int co = lane & 15;  // C col = co within ntile
    f32x4 accs[4] = {acc0, acc1, acc2, acc3};
#pragma unroll
    for (int nt = 0; nt < 4; ++nt) {
        float bias = b2[nt * 16 + co];
#pragma unroll
        for (int r = 0; r < 4; ++r) {
            int ow = ow0 + quad * 4 + r;  // C row = pixel
            if (ow < 381) {
                float v = fmaxf(accs[nt][r] + bias, 0.f);
                out[(((size_t)(b * 95 + oh) * 381) + ow) * 64 + nt * 16 + co] = f2bf(v);
            }
        }
    }
}

// ---- maxpool2 on conv2 output -> x2 fp32 [16,571520] (matches reshape order) ----
__global__ void k_pool2(const unsigned short* __restrict__ cin, float* __restrict__ x2) {
    int tid = blockIdx.x * 256 + threadIdx.x;
    int c = tid & 63;
    int t2 = tid >> 6;
    int w = t2 % 190;
    int t3 = t2 / 190;
    int h = t3 % 47;
    int b = t3 / 47;
    const unsigned short* p = cin + (((size_t)(b * 95 + 2 * h) * 381) + 2 * w) * 64 + c;
    float m = bf2f(p[0]);
    m = fmaxf(m, bf2f(p[64]));
    m = fmaxf(m, bf2f(p[381 * 64]));
    m = fmaxf(m, bf2f(p[381 * 64 + 64]));
    x2[tid] = m;
}

// ---- big FC: y512/z256 partials. 1024 K-slice blocks, 192 threads ----
// threads 0..127: w512 cols 4t..4t+3 ; threads 128..191: w256b cols 4(t-128)..
__global__ __launch_bounds__(192, 3) void k_fcbig(const float* __restrict__ x2,
                        const float* __restrict__ w512, const float* __restrict__ w256,
                        float* __restrict__ ppart) {
    __shared__ float xs[16 * FC_CH];
    int k0 = blockIdx.x * FC_CH;
    int cnt = FC_K - k0;
    if (cnt > FC_CH) cnt = FC_CH;
    if (cnt < 0) cnt = 0;
    int t = threadIdx.x;
    for (int b = 0; b < 16; ++b)
        for (int kk = t; kk < cnt; kk += 192)
            xs[b * FC_CH + kk] = x2[(size_t)b * FC_K + k0 + kk];
    __syncthreads();
    const float* wp;
    int ncols;
    if (t < 128) { wp = w512; ncols = 512; } else { wp = w256; ncols = 256; }
    int col0 = (t < 128) ? 4 * t : 4 * (t - 128);
    f32x4 acc[16];
#pragma unroll
    for (int b = 0; b < 16; ++b) acc[b] = (f32x4){0.f, 0.f, 0.f, 0.f};
    const float* wrow = wp + (size_t)k0 * ncols + col0;
#pragma unroll 2
    for (int kk = 0; kk < cnt; ++kk) {
        f32x4 wv = *(const f32x4*)(wrow);
        wrow += ncols;
#pragma unroll
        for (int b = 0; b < 16; ++b) acc[b] += wv * xs[b * FC_CH + kk];
    }
    int col = (t < 128) ? 4 * t : 512 + 4 * (t - 128);
    float* o = ppart + (size_t)blockIdx.x * 12288 + col;
#pragma unroll
    for (int b = 0; b < 16; ++b) *(f32x4*)(o + b * 768) = acc[b];
}

// ---- reduce partials over 1024 blocks + bias + leaky ----
__global__ void k_reduce_act(const float* __restrict__ ppart, const float* __restrict__ b512,
                             const float* __restrict__ b256, float* __restrict__ y512,
                             float* __restrict__ z256) {
    int tid = blockIdx.x * 256 + threadIdx.x;  // 12288 = 16*768
    float s = 0.f;
    const float* p = ppart + tid;
#pragma unroll 8
    for (int blk = 0; blk < FC_NB; ++blk) s += p[(size_t)blk * 12288];
    int b = tid / 768, col = tid % 768;
    if (col < 512) y512[b * 512 + col] = leaky(s + b512[col]);
    else z256[b * 256 + (col - 512)] = leaky(s + b256[col - 512]);
}

// ---- generic small GEMM + leaky: C[b][n] = leaky(A[b,:K] @ W[:,n] + bias[n]) ----
__global__ void k_gemm_small(const float* __restrict__ A, const float* __restrict__ W,
                             const float* __restrict__ bias, float* __restrict__ C,
                             int K, int N) {
    int tid = blockIdx.x * 256 + threadIdx.x;
    if (tid >= 16 * N) return;
    int n = tid % N, b = tid / N;
    float s = bias[n];
    const float* a = A + (size_t)b * K;
    const float* w = W + n;
    for (int k = 0; k < K; ++k) s += a[k] * w[(size_t)k * N];
    C[tid] = leaky(s);
}

// ---- softmax head: per (b,p): softmax(ycls[b,p,:13] @ wsm + bsm) ----
__global__ void k_head_sm(const float* __restrict__ ycls, const float* __restrict__ wsm,
                          const float* __restrict__ bsm, float* __restrict__ out) {
    int tid = blockIdx.x * 256 + threadIdx.x;
    if (tid >= 16 * 225) return;
    const float* in = ycls + tid * 13;
    float lo[13];
    float m = -1e30f;
#pragma unroll
    for (int o = 0; o < 13; ++o) {
        float s = bsm[o];
#pragma unroll
        for (int i = 0; i < 13; ++i) s += in[i] * wsm[i * 13 + o];
        lo[o] = s;
        m = fmaxf(m, s);
    }
    float sum = 0.f;
#pragma unroll
    for (int o = 0; o < 13; ++o) { lo[o] = expf(lo[o] - m); sum += lo[o]; }
    float inv = 1.f / sum;
#pragma unroll
    for (int o = 0; o < 13; ++o) out[tid * 13 + o] = lo[o] * inv;
}

// ---- sigmoid head: per (b,p): sigmoid(zreg[b,p,:4] @ wsig + bsig) ----
__global__ void k_head_sig(const float* __restrict__ zreg, const float* __restrict__ wsig,
                           const float* __restrict__ bsig, float* __restrict__ out) {
    int tid = blockIdx.x * 256 + threadIdx.x;
    if (tid >= 16 * 225) return;
    const float* in = zreg + tid * 4;
#pragma unroll
    for (int o = 0; o < 4; ++o) {
        float s = bsig[o];
#pragma unroll
        for (int i = 0; i < 4; ++i) s += in[i] * wsig[i * 4 + o];
        out[tid * 4 + o] = 1.f / (1.f + expf(-s));
    }
}

extern "C" void kernel_launch(void* const* d_in, const int* in_sizes, int n_in,
                              void* d_out, int out_size, void* d_ws, size_t ws_size,
                              hipStream_t stream) {
    const float* hid   = (const float*)d_in[0];
    const float* w1    = (const float*)d_in[1];
    const float* b1    = (const float*)d_in[2];
    const float* w2    = (const float*)d_in[3];
    const float* b2    = (const float*)d_in[4];
    const float* w512  = (const float*)d_in[5];
    const float* b512  = (const float*)d_in[6];
    const float* w256a = (const float*)d_in[7];
    const float* b256a = (const float*)d_in[8];
    const float* wcls  = (const float*)d_in[9];
    const float* bcls  = (const float*)d_in[10];
    const float* wsm   = (const float*)d_in[11];
    const float* bsm   = (const float*)d_in[12];
    const float* w256b = (const float*)d_in[13];
    const float* b256b = (const float*)d_in[14];
    const float* w128a = (const float*)d_in[15];
    const float* b128a = (const float*)d_in[16];
    const float* w128b = (const float*)d_in[17];
    const float* b128b = (const float*)d_in[18];
    const float* w64   = (const float*)d_in[19];
    const float* b64   = (const float*)d_in[20];
    const float* wreg  = (const float*)d_in[21];
    const float* breg  = (const float*)d_in[22];
    const float* wsig  = (const float*)d_in[23];
    const float* bsig  = (const float*)d_in[24];
    float* outp = (float*)d_out;

    char* ws = (char*)d_ws;
    size_t off = 0;
    auto alloc = [&](size_t bytes) {
        char* p = ws + off;
        off += (bytes + 255) & ~(size_t)255;
        return p;
    };
    unsigned short* x1  = (unsigned short*)alloc(38042624 + 512);  // +pad: conv2 A-loads overread <=190B
    char* big           = alloc(74119680);   // conv2out bf16; later aliased by ppart (50.3MB)
    unsigned short* c2o = (unsigned short*)big;
    float* ppart        = (float*)big;
    float* x2           = (float*)alloc(36577280);
    unsigned short* wfb = (unsigned short*)alloc(36864);
    float* y512v = (float*)alloc(32768);
    float* z256v = (float*)alloc(16384);
    float* y256v = (float*)alloc(16384);
    float* yclsv = (float*)alloc(187200);
    float* z128av = (float*)alloc(8192);
    float* z128bv = (float*)alloc(8192);
    float* z64v  = (float*)alloc(4096);
    float* zregv = (float*)alloc(57600);

    k_prep_wf<<<9, 256, 0, stream>>>(w2, wfb);
    k_conv1pool<<<74302, 256, 0, stream>>>(hid, w1, b1, x1);
    k_conv2<<<16 * 95 * 6, 256, 0, stream>>>(x1, wfb, b2, c2o);
    k_pool2<<<35720, 256, 0, stream>>>(c2o, x2);
    k_fcbig<<<FC_NB, 192, 0, stream>>>(x2, w512, w256b, ppart);
    k_reduce_act<<<48, 256, 0, stream>>>(ppart, b512, b256b, y512v, z256v);
    // classification branch
    k_gemm_small<<<16, 256, 0, stream>>>(y512v, w256a, b256a, y256v, 512, 256);
    k_gemm_small<<<183, 256, 0, stream>>>(y256v, wcls, bcls, yclsv, 256, 2925);
    k_head_sm<<<15, 256, 0, stream>>>(yclsv, wsm, bsm, outp);
    // regression branch
    k_gemm_small<<<8, 256, 0, stream>>>(z256v, w128a, b128a, z128av, 256, 128);
    k_gemm_small<<<8, 256, 0, stream>>>(z128av, w128b, b128b, z128bv, 128, 128);
    k_gemm_small<<<4, 256, 0, stream>>>(z128bv, w64, b64, z64v, 128, 64);
    k_gemm_small<<<57, 256, 0, stream>>>(z64v, wreg, breg, zregv, 64, 900);
    k_head_sig<<<15, 256, 0, stream>>>(zregv, wsig, bsig, outp + 46800);
}